// Round 14
// baseline (118.511 us; speedup 1.0000x reference)
//
#include <hip/hip_runtime.h>
#include <cfloat>

typedef _Float16 f16x8 __attribute__((ext_vector_type(8)));
typedef _Float16 f16x4 __attribute__((ext_vector_type(4)));
typedef float    f32x4 __attribute__((ext_vector_type(4)));

#define N_TOK 262144
#define DIM   64
#define KCB   512
#define TAU_T 0.004f       // flag threshold, half-distance units (R7-validated, 3-term)
#define FIXS  262144.0f    // 2^18 fixed-point scale

// swizzled byte offset of (code, dim-byte db) in an f16 codebook image:
// within a 128B row, XOR the 16B-slot bits with code&7 -> conflict-free b128
__device__ __forceinline__ int swz(int code, int db) {
    return code * 128 + (db ^ ((code & 7) << 4));
}

// ---------------------------------------------------------------------------
// prep: qneg[k] = -0.5*||v_k||^2 (f32), qd[k] = ||v_k||^2 (f64), pre-swizzled
// f16 hi/lo codebook images (2 x 64 KB, L2-resident), zero-fill of
// counts/flag_cnt/gsum.
// ---------------------------------------------------------------------------
__global__ __launch_bounds__(512) void prep_kernel(const float* __restrict__ vq,
        float* __restrict__ qneg, double* __restrict__ qd,
        char* __restrict__ vqh_img, char* __restrict__ vql_img,
        int* __restrict__ counts, int* __restrict__ flag_cnt,
        unsigned long long* __restrict__ gsum) {
    const int tid  = threadIdx.x;
    const int code = blockIdx.x * 32 + (tid >> 4);
    const int c4   = tid & 15;
    float4 g = *(const float4*)(vq + (size_t)code * DIM + c4 * 4);
    double s = 0.0;
    s = fma((double)g.x, (double)g.x, s);
    s = fma((double)g.y, (double)g.y, s);
    s = fma((double)g.z, (double)g.z, s);
    s = fma((double)g.w, (double)g.w, s);
#pragma unroll
    for (int sh = 1; sh < 16; sh <<= 1) s += __shfl_xor(s, sh, 64);
    if (c4 == 0) { qd[code] = s; qneg[code] = -(float)(0.5 * s); }

    float xs[4] = {g.x, g.y, g.z, g.w};
    f16x4 hi, lo;
#pragma unroll
    for (int e = 0; e < 4; ++e) {
        _Float16 h = (_Float16)xs[e];
        hi[e] = h;
        lo[e] = (_Float16)(xs[e] - (float)h);
    }
    *(f16x4*)(vqh_img + swz(code, c4 * 8)) = hi;
    *(f16x4*)(vql_img + swz(code, c4 * 8)) = lo;

    // zero-fill scratch accumulators
    int gid = blockIdx.x * 512 + tid;          // 0..8191
#pragma unroll
    for (int r = 0; r < 4; ++r) gsum[gid + r * 8192] = 0ull;
    if (blockIdx.x == 0) {
        counts[tid] = 0;
        if (tid == 0) *flag_cnt = 0;
    }
}

// ---------------------------------------------------------------------------
// MFMA argmin (R13 math, byte-identical per-wave work; block halved to
// 256 thr / 4 waves / 128 tokens so 4 independent barrier groups per CU
// can drift out of phase — R13's 8-wave blocks phase-locked the LDS/MFMA/
// VALU pipes behind one barrier).  acc = -q/2 + vh.xh + vl.xh + vh.xl;
// argmax acc == argmin dist.  A = v chunk (64 codes) hi/lo f16 in LDS dbuf
// (pre-swizzled image, linear copy); B = x rows, hi/lo f16 frags in
// REGISTERS.  D: row (grp*4+j) = code, col (li) = token.
// VGPR hard-capped at 64 via __launch_bounds__(256,8) (the R12 cliff).
// Hi image prefetch-held (2 int4); lo image loaded at the write point to
// keep the held live set at R13's level.
// ---------------------------------------------------------------------------
__global__ __launch_bounds__(256, 8) void argmin_mfma_kernel(
    const float* __restrict__ x, const float* __restrict__ vq,
    const float* __restrict__ qneg, int* __restrict__ idx_out,
    int* __restrict__ flag_cnt, int* __restrict__ flag_list,
    float* __restrict__ quant, int* __restrict__ counts,
    const char* __restrict__ vqh_img, const char* __restrict__ vql_img)
{
    __shared__ _Float16 vhh[2][4096];    // 2 x 8 KB dbuf (hi image)
    __shared__ _Float16 vhl[2][4096];    // 2 x 8 KB dbuf (lo image)
    __shared__ float    qneg_lds[KCB];   // 2 KB
    __shared__ int      idx_lds[128];
    __shared__ int      hist[KCB];       // 2 KB

    const int tid = threadIdx.x;
    const int m0  = blockIdx.x * 128;
    const int lane = tid & 63, w = tid >> 6;     // w in [0,4)
    const int grp = lane >> 4, li = lane & 15;

    hist[tid] = 0;
    hist[tid + 256] = 0;
    qneg_lds[tid] = qneg[tid];
    qneg_lds[tid + 256] = qneg[tid + 256];

    // B-frags: 2 tokens/thread (tt), hi/lo exact f16 split, from global once
    f16x8 bh[2][2], bl[2][2];
#pragma unroll
    for (int tt = 0; tt < 2; ++tt)
#pragma unroll
        for (int kk = 0; kk < 2; ++kk) {
            const float* p = x + (size_t)(m0 + w * 32 + tt * 16 + li) * DIM
                           + kk * 32 + grp * 8;
            float4 g0 = *(const float4*)p;
            float4 g1 = *(const float4*)(p + 4);
            float xs[8] = {g0.x, g0.y, g0.z, g0.w, g1.x, g1.y, g1.z, g1.w};
            f16x8 hi, lo;
#pragma unroll
            for (int e = 0; e < 8; ++e) {
                _Float16 h = (_Float16)xs[e];
                hi[e] = h;
                lo[e] = (_Float16)(xs[e] - (float)h);
            }
            bh[tt][kk] = hi; bl[tt][kk] = lo;
        }

    // stage chunk 0 (images pre-swizzled: linear 16B copies, 2 per image)
    *(int4*)((char*)vhh[0] + tid * 16)        = *(const int4*)(vqh_img + tid * 16);
    *(int4*)((char*)vhh[0] + tid * 16 + 4096) = *(const int4*)(vqh_img + tid * 16 + 4096);
    *(int4*)((char*)vhl[0] + tid * 16)        = *(const int4*)(vql_img + tid * 16);
    *(int4*)((char*)vhl[0] + tid * 16 + 4096) = *(const int4*)(vql_img + tid * 16 + 4096);

    // per-tt, two (max1,max2,argmax) chains (tc parity)
    float m1[2][2], m2[2][2]; int i1[2][2];
#pragma unroll
    for (int a = 0; a < 2; ++a)
#pragma unroll
        for (int b = 0; b < 2; ++b) { m1[a][b] = -FLT_MAX; m2[a][b] = -FLT_MAX; i1[a][b] = 0; }

    const int aswz = (grp << 4) ^ ((li & 7) << 4);

    for (int ch = 0; ch < 8; ++ch) {
        const int cur = ch & 1;
        __syncthreads();                 // buf[cur] staged; prior reads done
        int4 ph0, ph1;
        if (ch < 7) {                    // T14: issue next-chunk hi loads early
            ph0 = *(const int4*)(vqh_img + (ch + 1) * 8192 + tid * 16);
            ph1 = *(const int4*)(vqh_img + (ch + 1) * 8192 + tid * 16 + 4096);
        }

        const char* vbh = (const char*)vhh[cur];
        const char* vbl = (const char*)vhl[cur];
        f32x4 acc[4][2];
#pragma unroll
        for (int tc = 0; tc < 4; ++tc) { // acc init = -q/2 per code row
            float4 q = *(const float4*)&qneg_lds[ch * 64 + tc * 16 + grp * 4];
            f32x4 qi = {q.x, q.y, q.z, q.w};
            acc[tc][0] = qi; acc[tc][1] = qi;
        }
#pragma unroll
        for (int kk = 0; kk < 2; ++kk) {
            f16x8 ah[4], al[4];
#pragma unroll
            for (int tc = 0; tc < 4; ++tc) {
                int off = (tc * 16 + li) * 128 + (aswz ^ (kk << 6));
                ah[tc] = *(const f16x8*)(vbh + off);
                al[tc] = *(const f16x8*)(vbl + off);
            }
#pragma unroll
            for (int tc = 0; tc < 4; ++tc)   // 8 independent chains per pass
#pragma unroll
                for (int tt = 0; tt < 2; ++tt)
                    acc[tc][tt] = __builtin_amdgcn_mfma_f32_16x16x32_f16(ah[tc], bh[tt][kk], acc[tc][tt], 0, 0, 0);
#pragma unroll
            for (int tc = 0; tc < 4; ++tc)
#pragma unroll
                for (int tt = 0; tt < 2; ++tt)
                    acc[tc][tt] = __builtin_amdgcn_mfma_f32_16x16x32_f16(al[tc], bh[tt][kk], acc[tc][tt], 0, 0, 0);
#pragma unroll
            for (int tc = 0; tc < 4; ++tc)
#pragma unroll
                for (int tt = 0; tt < 2; ++tt)
                    acc[tc][tt] = __builtin_amdgcn_mfma_f32_16x16x32_f16(ah[tc], bl[tt][kk], acc[tc][tt], 0, 0, 0);
        }
        // epilogue: 32 scores/thread, 4 independent min-chains (R7-exact)
#pragma unroll
        for (int tc = 0; tc < 4; ++tc) {
            const int cch = tc & 1;
            const int idv = ch * 64 + tc * 16 + grp * 4;
#pragma unroll
            for (int tt = 0; tt < 2; ++tt)
#pragma unroll
                for (int j = 0; j < 4; ++j) {
                    float t = acc[tc][tt][j];
                    float old1 = m1[tt][cch];
                    bool c = t > old1;
                    m2[tt][cch] = fmaxf(m2[tt][cch], c ? old1 : t);
                    m1[tt][cch] = c ? t : old1;
                    i1[tt][cch] = c ? (idv + j) : i1[tt][cch];
                }
        }
        if (ch < 7) {                    // write hi (held), copy lo (load+write)
            *(int4*)((char*)vhh[cur ^ 1] + tid * 16)        = ph0;
            *(int4*)((char*)vhh[cur ^ 1] + tid * 16 + 4096) = ph1;
            int4 pl0 = *(const int4*)(vql_img + (ch + 1) * 8192 + tid * 16);
            int4 pl1 = *(const int4*)(vql_img + (ch + 1) * 8192 + tid * 16 + 4096);
            *(int4*)((char*)vhl[cur ^ 1] + tid * 16)        = pl0;
            *(int4*)((char*)vhl[cur ^ 1] + tid * 16 + 4096) = pl1;
        }
    }

    // per-tt: merge the two chains, then the 4 grp-lanes per token (col = li)
#pragma unroll
    for (int tt = 0; tt < 2; ++tt) {
        float v1 = m1[tt][0], v2 = m2[tt][0];
        int ix = i1[tt][0];
        {
            bool c = (m1[tt][1] > v1) || (m1[tt][1] == v1 && i1[tt][1] < ix);
            v2 = fmaxf(fmaxf(v2, m2[tt][1]), fminf(v1, m1[tt][1]));
            v1 = c ? m1[tt][1] : v1;
            ix = c ? i1[tt][1] : ix;
        }
#pragma unroll
        for (int s = 16; s <= 32; s <<= 1) {
            float o1 = __shfl_xor(v1, s, 64);
            float o2 = __shfl_xor(v2, s, 64);
            int   oi = __shfl_xor(ix, s, 64);
            v2 = fmaxf(v2, fmaxf(o2, fminf(v1, o1)));
            bool c = (o1 > v1) || (o1 == v1 && oi < ix);
            v1 = c ? o1 : v1;
            ix = c ? oi : ix;
        }
        if (lane < 16) {
            int tokloc = w * 32 + tt * 16 + li;
            idx_lds[tokloc] = ix;
            idx_out[m0 + tokloc] = ix;
            if (v1 - v2 < TAU_T) {
                int p = atomicAdd(flag_cnt, 1);
                flag_list[p] = m0 + tokloc;
            }
        }
    }
    __syncthreads();

    if (tid < 128) atomicAdd(&hist[idx_lds[tid]], 1);

    // quantized gather (refine later overwrites flagged rows)
#pragma unroll
    for (int jj = 0; jj < 8; ++jj) {
        int id = tid + jj * 256;         // 2048 float4s = 128 rows x 16
        int row = id >> 4, c4 = id & 15;
        int k = idx_lds[row];
        float4 v = *(const float4*)(vq + (size_t)k * DIM + c4 * 4);
        *(float4*)(quant + (size_t)(m0 + row) * DIM + c4 * 4) = v;
    }
    __syncthreads();
    if (hist[tid] > 0) atomicAdd(&counts[tid], hist[tid]);
    if (hist[tid + 256] > 0) atomicAdd(&counts[tid + 256], hist[tid + 256]);
}

// ---------------------------------------------------------------------------
// Exact fp64 re-argmin of flagged tokens (validated).  256 thr (xd[64] fits
// in registers), vq from global (L2-resident).  Patches counts[] on flips.
// ---------------------------------------------------------------------------
__global__ __launch_bounds__(256) void refine_kernel(
    const float* __restrict__ x, const float* __restrict__ vq,
    const double* __restrict__ qd,
    const int* __restrict__ flag_cnt, const int* __restrict__ flag_list,
    int* __restrict__ idx_out, float* __restrict__ quant,
    int* __restrict__ counts)
{
    const int cnt = *flag_cnt;
    if (cnt <= 0) return;
    const int tid = threadIdx.x;
    const int lane = tid & 63, w = tid >> 6;

    for (int fi = blockIdx.x * 4 + w; fi < cnt; fi += 1024) {
        int token = flag_list[fi];
        const float* xr = x + (size_t)token * DIM;
        double xd[DIM];
#pragma unroll
        for (int dq = 0; dq < 16; ++dq) {
            float4 g = *(const float4*)(xr + dq * 4);
            xd[dq * 4 + 0] = (double)g.x;
            xd[dq * 4 + 1] = (double)g.y;
            xd[dq * 4 + 2] = (double)g.z;
            xd[dq * 4 + 3] = (double)g.w;
        }
        double best = DBL_MAX; int bc = 0;
#pragma unroll 1
        for (int jj = 0; jj < 8; ++jj) {
            int c = lane + jj * 64;
            const float* vr = vq + (size_t)c * DIM;
            double s0 = 0.0, s1 = 0.0, s2 = 0.0, s3 = 0.0;
#pragma unroll
            for (int dq = 0; dq < 16; dq += 4) {
                float4 v0 = *(const float4*)(vr + dq * 4);
                float4 v1 = *(const float4*)(vr + dq * 4 + 4);
                float4 v2 = *(const float4*)(vr + dq * 4 + 8);
                float4 v3 = *(const float4*)(vr + dq * 4 + 12);
                s0 = fma(xd[dq*4+0], (double)v0.x, s0); s0 = fma(xd[dq*4+1], (double)v0.y, s0);
                s0 = fma(xd[dq*4+2], (double)v0.z, s0); s0 = fma(xd[dq*4+3], (double)v0.w, s0);
                s1 = fma(xd[dq*4+4], (double)v1.x, s1); s1 = fma(xd[dq*4+5], (double)v1.y, s1);
                s1 = fma(xd[dq*4+6], (double)v1.z, s1); s1 = fma(xd[dq*4+7], (double)v1.w, s1);
                s2 = fma(xd[dq*4+8], (double)v2.x, s2); s2 = fma(xd[dq*4+9], (double)v2.y, s2);
                s2 = fma(xd[dq*4+10], (double)v2.z, s2); s2 = fma(xd[dq*4+11], (double)v2.w, s2);
                s3 = fma(xd[dq*4+12], (double)v3.x, s3); s3 = fma(xd[dq*4+13], (double)v3.y, s3);
                s3 = fma(xd[dq*4+14], (double)v3.z, s3); s3 = fma(xd[dq*4+15], (double)v3.w, s3);
            }
            double dist = qd[c] - 2.0 * ((s0 + s1) + (s2 + s3));
            if (dist < best) { best = dist; bc = c; }
        }
#pragma unroll
        for (int sh = 1; sh < 64; sh <<= 1) {
            double ob = __shfl_xor(best, sh, 64);
            int    oc = __shfl_xor(bc, sh, 64);
            bool c = (ob < best) || (ob == best && oc < bc);
            best = c ? ob : best;
            bc   = c ? oc : bc;
        }
        if (lane == 0) {
            int old = idx_out[token];
            if (old != bc) {
                idx_out[token] = bc;
                atomicAdd(&counts[old], -1);
                atomicAdd(&counts[bc], 1);
            }
        }
        if (lane < 16) {
            float4 v = *(const float4*)(vq + (size_t)bc * DIM + lane * 4);
            *(float4*)(quant + (size_t)token * DIM + lane * 4) = v;
        }
    }
}

// ---------------------------------------------------------------------------
// Exclusive scan of counts -> cursor; EMA for centroid_n output.
// ---------------------------------------------------------------------------
__global__ __launch_bounds__(512) void scan_ema_kernel(
    const int* __restrict__ counts, int* __restrict__ cursor,
    const float* __restrict__ cn_old, float* __restrict__ out_cn)
{
    __shared__ int s[KCB];
    const int tid = threadIdx.x;
    int my = counts[tid];
    s[tid] = my;
    __syncthreads();
    for (int off = 1; off < KCB; off <<= 1) {
        int v = s[tid];
        int a = (tid >= off) ? s[tid - off] : 0;
        __syncthreads();
        s[tid] = v + a;
        __syncthreads();
    }
    cursor[tid] = s[tid] - my;
    out_cn[tid] = cn_old[tid] * 0.99f + (float)my * 0.01f;
}

// ---------------------------------------------------------------------------
// Counting-sort scatter: LDS-local histogram, one global atomic per
// (block,code), packed (k<<18 | t).
// ---------------------------------------------------------------------------
__global__ __launch_bounds__(512) void scatter_kernel(
    const int* __restrict__ idx, int* __restrict__ cursor,
    int* __restrict__ sorted)
{
    __shared__ int lhist[KCB];
    __shared__ int lbase[KCB];
    const int tid = threadIdx.x;
    const int t0 = blockIdx.x * 1024;

    lhist[tid] = 0;
    __syncthreads();
    int k0 = idx[t0 + tid];
    int k1 = idx[t0 + 512 + tid];
    atomicAdd(&lhist[k0], 1);
    atomicAdd(&lhist[k1], 1);
    __syncthreads();
    int h = lhist[tid];
    lbase[tid] = (h > 0) ? atomicAdd(&cursor[tid], h) : 0;
    __syncthreads();
    lhist[tid] = 0;
    __syncthreads();
    int s0 = atomicAdd(&lhist[k0], 1);
    sorted[lbase[k0] + s0] = (k0 << 18) | (t0 + tid);
    int s1 = atomicAdd(&lhist[k1], 1);
    sorted[lbase[k1] + s1] = (k1 << 18) | (t0 + 512 + tid);
}

// ---------------------------------------------------------------------------
// Gather-reduce over sorted entries; int64 fixed-point, order-independent.
// ---------------------------------------------------------------------------
__global__ __launch_bounds__(256) void gather_kernel(
    const float* __restrict__ x, const int* __restrict__ sorted,
    unsigned long long* __restrict__ gsum)
{
    __shared__ int le[256];
    const int tid = threadIdx.x;
    le[tid] = sorted[blockIdx.x * 256 + tid];
    __syncthreads();
    const int lane = tid & 63, w = tid >> 6;
    const int base = w * 64;

    int e = le[base];
    int kc = e >> 18, t = e & 0x3FFFF;
    float v = x[(size_t)t * DIM + lane];
    int kp = kc;
    long long acc = 0;
#pragma unroll 4
    for (int i = 1; i < 64; ++i) {
        int e1 = le[base + i];
        int k1 = e1 >> 18, t1 = e1 & 0x3FFFF;
        float v1 = x[(size_t)t1 * DIM + lane];
        if (kc != kp) {
            atomicAdd(&gsum[kp * DIM + lane], (unsigned long long)acc);
            acc = 0; kp = kc;
        }
        acc += (long long)rintf(v * FIXS);
        kc = k1; v = v1;
    }
    if (kc != kp) {
        atomicAdd(&gsum[kp * DIM + lane], (unsigned long long)acc);
        acc = 0; kp = kc;
    }
    acc += (long long)rintf(v * FIXS);
    atomicAdd(&gsum[kp * DIM + lane], (unsigned long long)acc);
}

// ---------------------------------------------------------------------------
// Finalize: EMA + division for centroid_sum and vq outputs.
// ---------------------------------------------------------------------------
__global__ __launch_bounds__(512) void finalize_kernel(
    const unsigned long long* __restrict__ gsum,
    const float* __restrict__ cs_old, const float* __restrict__ out_cn,
    float* __restrict__ out_vq, float* __restrict__ out_cs)
{
    int gid = blockIdx.x * 512 + threadIdx.x;
    if (gid >= KCB * DIM) return;
    int k = gid >> 6;
    long long g = (long long)gsum[gid];
    float scs = (float)((double)g * (1.0 / 262144.0));
    float ncs = cs_old[gid] * 0.99f + scs * 0.01f;
    out_cs[gid] = ncs;
    out_vq[gid] = ncs / out_cn[k];
}

// ---------------------------------------------------------------------------
extern "C" void kernel_launch(void* const* d_in, const int* in_sizes, int n_in,
                              void* d_out, int out_size, void* d_ws, size_t ws_size,
                              hipStream_t stream)
{
    const float* x      = (const float*)d_in[0];
    const float* vq     = (const float*)d_in[1];
    const float* cs_old = (const float*)d_in[2];
    const float* cn_old = (const float*)d_in[3];

    float* out_q  = (float*)d_out;
    float* out_vq = out_q + (size_t)N_TOK * DIM;
    float* out_cs = out_vq + (size_t)KCB * DIM;
    float* out_cn = out_cs + (size_t)KCB * DIM;

    char* ws = (char*)d_ws;
    int*    idx       = (int*)(ws);                              // 1 MB
    int*    flag_list = (int*)(ws + (1 << 20));                  // 1 MB (reused as sorted)
    int*    sorted    = flag_list;                               // refine consumes flags first
    int*    flag_cnt  = (int*)(ws + (2 << 20));                  // 4 B
    float*  qneg      = (float*)(ws + (2 << 20) + 1024);         // 2 KB
    double* qd        = (double*)(ws + (2 << 20) + 4096);        // 4 KB
    int*    counts    = (int*)(ws + (2 << 20) + 8192);           // 2 KB
    int*    cursor    = (int*)(ws + (2 << 20) + 10240);          // 2 KB
    unsigned long long* gsum =
        (unsigned long long*)(ws + (2 << 20) + 12288);           // 256 KB
    char*   vqh_img   = ws + (2 << 20) + 12288 + 262144;         // 64 KB
    char*   vql_img   = vqh_img + 65536;                         // 64 KB

    prep_kernel<<<16, 512, 0, stream>>>(vq, qneg, qd, vqh_img, vql_img,
                                        counts, flag_cnt, gsum);
    argmin_mfma_kernel<<<N_TOK / 128, 256, 0, stream>>>(x, vq, qneg, idx,
                                                        flag_cnt, flag_list,
                                                        out_q, counts,
                                                        vqh_img, vql_img);
    refine_kernel<<<256, 256, 0, stream>>>(x, vq, qd, flag_cnt, flag_list,
                                           idx, out_q, counts);
    scan_ema_kernel<<<1, 512, 0, stream>>>(counts, cursor, cn_old, out_cn);
    scatter_kernel<<<N_TOK / 1024, 512, 0, stream>>>(idx, cursor, sorted);
    gather_kernel<<<N_TOK / 256, 256, 0, stream>>>(x, sorted, gsum);
    finalize_kernel<<<KCB * DIM / 512, 512, 0, stream>>>(gsum, cs_old, out_cn,
                                                         out_vq, out_cs);
}

// Round 15
// 113.639 us; speedup vs baseline: 1.0429x; 1.0429x over previous
//
#include <hip/hip_runtime.h>
#include <cfloat>

typedef _Float16 f16x8 __attribute__((ext_vector_type(8)));
typedef _Float16 f16x4 __attribute__((ext_vector_type(4)));
typedef float    f32x4 __attribute__((ext_vector_type(4)));

#define N_TOK 262144
#define DIM   64
#define KCB   512
#define TAU_T 0.004f       // flag threshold, half-distance units (R7-validated, 3-term)
#define FIXS  262144.0f    // 2^18 fixed-point scale

// swizzled byte offset of (code, dim-byte db) in an f16 codebook image:
// within a 128B row, XOR the 16B-slot bits with code&7 -> conflict-free b128
__device__ __forceinline__ int swz(int code, int db) {
    return code * 128 + (db ^ ((code & 7) << 4));
}

// ---------------------------------------------------------------------------
// prep: qneg[k] = -0.5*||v_k||^2 (f32), qd[k] = ||v_k||^2 (f64), pre-swizzled
// f16 hi/lo codebook images (2 x 64 KB, L2-resident), zero-fill of
// counts/flag_cnt/gsum.
// ---------------------------------------------------------------------------
__global__ __launch_bounds__(512) void prep_kernel(const float* __restrict__ vq,
        float* __restrict__ qneg, double* __restrict__ qd,
        char* __restrict__ vqh_img, char* __restrict__ vql_img,
        int* __restrict__ counts, int* __restrict__ flag_cnt,
        unsigned long long* __restrict__ gsum) {
    const int tid  = threadIdx.x;
    const int code = blockIdx.x * 32 + (tid >> 4);
    const int c4   = tid & 15;
    float4 g = *(const float4*)(vq + (size_t)code * DIM + c4 * 4);
    double s = 0.0;
    s = fma((double)g.x, (double)g.x, s);
    s = fma((double)g.y, (double)g.y, s);
    s = fma((double)g.z, (double)g.z, s);
    s = fma((double)g.w, (double)g.w, s);
#pragma unroll
    for (int sh = 1; sh < 16; sh <<= 1) s += __shfl_xor(s, sh, 64);
    if (c4 == 0) { qd[code] = s; qneg[code] = -(float)(0.5 * s); }

    float xs[4] = {g.x, g.y, g.z, g.w};
    f16x4 hi, lo;
#pragma unroll
    for (int e = 0; e < 4; ++e) {
        _Float16 h = (_Float16)xs[e];
        hi[e] = h;
        lo[e] = (_Float16)(xs[e] - (float)h);
    }
    *(f16x4*)(vqh_img + swz(code, c4 * 8)) = hi;
    *(f16x4*)(vql_img + swz(code, c4 * 8)) = lo;

    // zero-fill scratch accumulators
    int gid = blockIdx.x * 512 + tid;          // 0..8191
#pragma unroll
    for (int r = 0; r < 4; ++r) gsum[gid + r * 8192] = 0ull;
    if (blockIdx.x == 0) {
        counts[tid] = 0;
        if (tid == 0) *flag_cnt = 0;
    }
}

// ---------------------------------------------------------------------------
// MFMA argmin (R7/R13 structure, 76us twice-validated; 64 VGPR, the
// occupancy-tier boundary): acc = -q/2 + vh.xh + vl.xh + vh.xl
// (argmax acc == argmin dist).  512 thr = 8 waves; 256 tokens/block
// (32/wave, tt=2 subtiles).  A = v chunk (64 codes) hi/lo f16 in LDS dbuf
// (pre-swizzled image, linear copy); B = x rows, hi/lo f16 frags in
// REGISTERS (chunk-invariant).  D: row (grp*4+j) = code, col (li) = token.
// 8 independent acc chains.
// MEASURED NEIGHBORHOOD (do not revisit): med3 epilogue +4 VGPR -> 97us
// (R12); 4-wave blocks -> 88us (R14); 2 blocks/CU code-resident -> 109-113us
// (R10/R11); code-split -> 216us (R9); operand swap -> 122us (R5).
// ---------------------------------------------------------------------------
__global__ __launch_bounds__(512, 2) void argmin_mfma_kernel(
    const float* __restrict__ x, const float* __restrict__ vq,
    const float* __restrict__ qneg, int* __restrict__ idx_out,
    int* __restrict__ flag_cnt, int* __restrict__ flag_list,
    float* __restrict__ quant, int* __restrict__ counts,
    const char* __restrict__ vqh_img, const char* __restrict__ vql_img)
{
    __shared__ _Float16 vhh[2][4096];    // 2 x 8 KB dbuf (hi image)
    __shared__ _Float16 vhl[2][4096];    // 2 x 8 KB dbuf (lo image)
    __shared__ float    qneg_lds[KCB];   // 2 KB
    __shared__ int      idx_lds[256];    // 1 KB
    __shared__ int      hist[KCB];       // 2 KB

    const int tid = threadIdx.x;
    const int m0  = blockIdx.x * 256;
    const int lane = tid & 63, w = tid >> 6;
    const int grp = lane >> 4, li = lane & 15;

    hist[tid] = 0;
    qneg_lds[tid] = qneg[tid];

    // B-frags: 2 tokens/thread (tt), hi/lo exact f16 split, from global once
    f16x8 bh[2][2], bl[2][2];
#pragma unroll
    for (int tt = 0; tt < 2; ++tt)
#pragma unroll
        for (int kk = 0; kk < 2; ++kk) {
            const float* p = x + (size_t)(m0 + w * 32 + tt * 16 + li) * DIM
                           + kk * 32 + grp * 8;
            float4 g0 = *(const float4*)p;
            float4 g1 = *(const float4*)(p + 4);
            float xs[8] = {g0.x, g0.y, g0.z, g0.w, g1.x, g1.y, g1.z, g1.w};
            f16x8 hi, lo;
#pragma unroll
            for (int e = 0; e < 8; ++e) {
                _Float16 h = (_Float16)xs[e];
                hi[e] = h;
                lo[e] = (_Float16)(xs[e] - (float)h);
            }
            bh[tt][kk] = hi; bl[tt][kk] = lo;
        }

    // stage chunk 0 (images pre-swizzled: linear 16B copies)
    *(int4*)((char*)vhh[0] + tid * 16) = *(const int4*)(vqh_img + tid * 16);
    *(int4*)((char*)vhl[0] + tid * 16) = *(const int4*)(vql_img + tid * 16);

    // per-tt, two (max1,max2,argmax) chains (tc parity)
    float m1[2][2], m2[2][2]; int i1[2][2];
#pragma unroll
    for (int a = 0; a < 2; ++a)
#pragma unroll
        for (int b = 0; b < 2; ++b) { m1[a][b] = -FLT_MAX; m2[a][b] = -FLT_MAX; i1[a][b] = 0; }

    const int aswz = (grp << 4) ^ ((li & 7) << 4);

    for (int ch = 0; ch < 8; ++ch) {
        const int cur = ch & 1;
        __syncthreads();                 // buf[cur] staged; prior reads done
        int4 ph, pl;
        if (ch < 7) {                    // T14: issue next-chunk loads early
            ph = *(const int4*)(vqh_img + (ch + 1) * 8192 + tid * 16);
            pl = *(const int4*)(vql_img + (ch + 1) * 8192 + tid * 16);
        }

        const char* vbh = (const char*)vhh[cur];
        const char* vbl = (const char*)vhl[cur];
        f32x4 acc[4][2];
#pragma unroll
        for (int tc = 0; tc < 4; ++tc) { // acc init = -q/2 per code row
            float4 q = *(const float4*)&qneg_lds[ch * 64 + tc * 16 + grp * 4];
            f32x4 qi = {q.x, q.y, q.z, q.w};
            acc[tc][0] = qi; acc[tc][1] = qi;
        }
#pragma unroll
        for (int kk = 0; kk < 2; ++kk) {
            f16x8 ah[4], al[4];
#pragma unroll
            for (int tc = 0; tc < 4; ++tc) {
                int off = (tc * 16 + li) * 128 + (aswz ^ (kk << 6));
                ah[tc] = *(const f16x8*)(vbh + off);
                al[tc] = *(const f16x8*)(vbl + off);
            }
#pragma unroll
            for (int tc = 0; tc < 4; ++tc)   // 8 independent chains per pass
#pragma unroll
                for (int tt = 0; tt < 2; ++tt)
                    acc[tc][tt] = __builtin_amdgcn_mfma_f32_16x16x32_f16(ah[tc], bh[tt][kk], acc[tc][tt], 0, 0, 0);
#pragma unroll
            for (int tc = 0; tc < 4; ++tc)
#pragma unroll
                for (int tt = 0; tt < 2; ++tt)
                    acc[tc][tt] = __builtin_amdgcn_mfma_f32_16x16x32_f16(al[tc], bh[tt][kk], acc[tc][tt], 0, 0, 0);
#pragma unroll
            for (int tc = 0; tc < 4; ++tc)
#pragma unroll
                for (int tt = 0; tt < 2; ++tt)
                    acc[tc][tt] = __builtin_amdgcn_mfma_f32_16x16x32_f16(ah[tc], bl[tt][kk], acc[tc][tt], 0, 0, 0);
        }
        // epilogue: 32 scores/thread, 4 independent min-chains (R7-exact)
#pragma unroll
        for (int tc = 0; tc < 4; ++tc) {
            const int cch = tc & 1;
            const int idv = ch * 64 + tc * 16 + grp * 4;
#pragma unroll
            for (int tt = 0; tt < 2; ++tt)
#pragma unroll
                for (int j = 0; j < 4; ++j) {
                    float t = acc[tc][tt][j];
                    float old1 = m1[tt][cch];
                    bool c = t > old1;
                    m2[tt][cch] = fmaxf(m2[tt][cch], c ? old1 : t);
                    m1[tt][cch] = c ? t : old1;
                    i1[tt][cch] = c ? (idv + j) : i1[tt][cch];
                }
        }
        if (ch < 7) {                    // stage into the freed buffer
            *(int4*)((char*)vhh[cur ^ 1] + tid * 16) = ph;
            *(int4*)((char*)vhl[cur ^ 1] + tid * 16) = pl;
        }
    }

    // per-tt: merge the two chains, then the 4 grp-lanes per token (col = li)
#pragma unroll
    for (int tt = 0; tt < 2; ++tt) {
        float v1 = m1[tt][0], v2 = m2[tt][0];
        int ix = i1[tt][0];
        {
            bool c = (m1[tt][1] > v1) || (m1[tt][1] == v1 && i1[tt][1] < ix);
            v2 = fmaxf(fmaxf(v2, m2[tt][1]), fminf(v1, m1[tt][1]));
            v1 = c ? m1[tt][1] : v1;
            ix = c ? i1[tt][1] : ix;
        }
#pragma unroll
        for (int s = 16; s <= 32; s <<= 1) {
            float o1 = __shfl_xor(v1, s, 64);
            float o2 = __shfl_xor(v2, s, 64);
            int   oi = __shfl_xor(ix, s, 64);
            v2 = fmaxf(v2, fmaxf(o2, fminf(v1, o1)));
            bool c = (o1 > v1) || (o1 == v1 && oi < ix);
            v1 = c ? o1 : v1;
            ix = c ? oi : ix;
        }
        if (lane < 16) {
            int tokloc = w * 32 + tt * 16 + li;
            idx_lds[tokloc] = ix;
            idx_out[m0 + tokloc] = ix;
            if (v1 - v2 < TAU_T) {
                int p = atomicAdd(flag_cnt, 1);
                flag_list[p] = m0 + tokloc;
            }
        }
    }
    __syncthreads();

    if (tid < 256) atomicAdd(&hist[idx_lds[tid]], 1);

    // quantized gather (refine later overwrites flagged rows)
#pragma unroll
    for (int jj = 0; jj < 8; ++jj) {
        int id = tid + jj * 512;
        int row = id >> 4, c4 = id & 15;
        int k = idx_lds[row];
        float4 v = *(const float4*)(vq + (size_t)k * DIM + c4 * 4);
        *(float4*)(quant + (size_t)(m0 + row) * DIM + c4 * 4) = v;
    }
    __syncthreads();
    if (hist[tid] > 0) atomicAdd(&counts[tid], hist[tid]);
}

// ---------------------------------------------------------------------------
// Exact fp64 re-argmin of flagged tokens (validated).  256 thr (xd[64] fits
// in registers), vq from global (L2-resident).  Patches counts[] on flips.
// ---------------------------------------------------------------------------
__global__ __launch_bounds__(256) void refine_kernel(
    const float* __restrict__ x, const float* __restrict__ vq,
    const double* __restrict__ qd,
    const int* __restrict__ flag_cnt, const int* __restrict__ flag_list,
    int* __restrict__ idx_out, float* __restrict__ quant,
    int* __restrict__ counts)
{
    const int cnt = *flag_cnt;
    if (cnt <= 0) return;
    const int tid = threadIdx.x;
    const int lane = tid & 63, w = tid >> 6;

    for (int fi = blockIdx.x * 4 + w; fi < cnt; fi += 1024) {
        int token = flag_list[fi];
        const float* xr = x + (size_t)token * DIM;
        double xd[DIM];
#pragma unroll
        for (int dq = 0; dq < 16; ++dq) {
            float4 g = *(const float4*)(xr + dq * 4);
            xd[dq * 4 + 0] = (double)g.x;
            xd[dq * 4 + 1] = (double)g.y;
            xd[dq * 4 + 2] = (double)g.z;
            xd[dq * 4 + 3] = (double)g.w;
        }
        double best = DBL_MAX; int bc = 0;
#pragma unroll 1
        for (int jj = 0; jj < 8; ++jj) {
            int c = lane + jj * 64;
            const float* vr = vq + (size_t)c * DIM;
            double s0 = 0.0, s1 = 0.0, s2 = 0.0, s3 = 0.0;
#pragma unroll
            for (int dq = 0; dq < 16; dq += 4) {
                float4 v0 = *(const float4*)(vr + dq * 4);
                float4 v1 = *(const float4*)(vr + dq * 4 + 4);
                float4 v2 = *(const float4*)(vr + dq * 4 + 8);
                float4 v3 = *(const float4*)(vr + dq * 4 + 12);
                s0 = fma(xd[dq*4+0], (double)v0.x, s0); s0 = fma(xd[dq*4+1], (double)v0.y, s0);
                s0 = fma(xd[dq*4+2], (double)v0.z, s0); s0 = fma(xd[dq*4+3], (double)v0.w, s0);
                s1 = fma(xd[dq*4+4], (double)v1.x, s1); s1 = fma(xd[dq*4+5], (double)v1.y, s1);
                s1 = fma(xd[dq*4+6], (double)v1.z, s1); s1 = fma(xd[dq*4+7], (double)v1.w, s1);
                s2 = fma(xd[dq*4+8], (double)v2.x, s2); s2 = fma(xd[dq*4+9], (double)v2.y, s2);
                s2 = fma(xd[dq*4+10], (double)v2.z, s2); s2 = fma(xd[dq*4+11], (double)v2.w, s2);
                s3 = fma(xd[dq*4+12], (double)v3.x, s3); s3 = fma(xd[dq*4+13], (double)v3.y, s3);
                s3 = fma(xd[dq*4+14], (double)v3.z, s3); s3 = fma(xd[dq*4+15], (double)v3.w, s3);
            }
            double dist = qd[c] - 2.0 * ((s0 + s1) + (s2 + s3));
            if (dist < best) { best = dist; bc = c; }
        }
#pragma unroll
        for (int sh = 1; sh < 64; sh <<= 1) {
            double ob = __shfl_xor(best, sh, 64);
            int    oc = __shfl_xor(bc, sh, 64);
            bool c = (ob < best) || (ob == best && oc < bc);
            best = c ? ob : best;
            bc   = c ? oc : bc;
        }
        if (lane == 0) {
            int old = idx_out[token];
            if (old != bc) {
                idx_out[token] = bc;
                atomicAdd(&counts[old], -1);
                atomicAdd(&counts[bc], 1);
            }
        }
        if (lane < 16) {
            float4 v = *(const float4*)(vq + (size_t)bc * DIM + lane * 4);
            *(float4*)(quant + (size_t)token * DIM + lane * 4) = v;
        }
    }
}

// ---------------------------------------------------------------------------
// Exclusive scan of counts -> cursor; EMA for centroid_n output.
// ---------------------------------------------------------------------------
__global__ __launch_bounds__(512) void scan_ema_kernel(
    const int* __restrict__ counts, int* __restrict__ cursor,
    const float* __restrict__ cn_old, float* __restrict__ out_cn)
{
    __shared__ int s[KCB];
    const int tid = threadIdx.x;
    int my = counts[tid];
    s[tid] = my;
    __syncthreads();
    for (int off = 1; off < KCB; off <<= 1) {
        int v = s[tid];
        int a = (tid >= off) ? s[tid - off] : 0;
        __syncthreads();
        s[tid] = v + a;
        __syncthreads();
    }
    cursor[tid] = s[tid] - my;
    out_cn[tid] = cn_old[tid] * 0.99f + (float)my * 0.01f;
}

// ---------------------------------------------------------------------------
// Counting-sort scatter: LDS-local histogram, one global atomic per
// (block,code), packed (k<<18 | t).
// ---------------------------------------------------------------------------
__global__ __launch_bounds__(512) void scatter_kernel(
    const int* __restrict__ idx, int* __restrict__ cursor,
    int* __restrict__ sorted)
{
    __shared__ int lhist[KCB];
    __shared__ int lbase[KCB];
    const int tid = threadIdx.x;
    const int t0 = blockIdx.x * 1024;

    lhist[tid] = 0;
    __syncthreads();
    int k0 = idx[t0 + tid];
    int k1 = idx[t0 + 512 + tid];
    atomicAdd(&lhist[k0], 1);
    atomicAdd(&lhist[k1], 1);
    __syncthreads();
    int h = lhist[tid];
    lbase[tid] = (h > 0) ? atomicAdd(&cursor[tid], h) : 0;
    __syncthreads();
    lhist[tid] = 0;
    __syncthreads();
    int s0 = atomicAdd(&lhist[k0], 1);
    sorted[lbase[k0] + s0] = (k0 << 18) | (t0 + tid);
    int s1 = atomicAdd(&lhist[k1], 1);
    sorted[lbase[k1] + s1] = (k1 << 18) | (t0 + 512 + tid);
}

// ---------------------------------------------------------------------------
// Gather-reduce over sorted entries; int64 fixed-point, order-independent.
// ---------------------------------------------------------------------------
__global__ __launch_bounds__(256) void gather_kernel(
    const float* __restrict__ x, const int* __restrict__ sorted,
    unsigned long long* __restrict__ gsum)
{
    __shared__ int le[256];
    const int tid = threadIdx.x;
    le[tid] = sorted[blockIdx.x * 256 + tid];
    __syncthreads();
    const int lane = tid & 63, w = tid >> 6;
    const int base = w * 64;

    int e = le[base];
    int kc = e >> 18, t = e & 0x3FFFF;
    float v = x[(size_t)t * DIM + lane];
    int kp = kc;
    long long acc = 0;
#pragma unroll 4
    for (int i = 1; i < 64; ++i) {
        int e1 = le[base + i];
        int k1 = e1 >> 18, t1 = e1 & 0x3FFFF;
        float v1 = x[(size_t)t1 * DIM + lane];
        if (kc != kp) {
            atomicAdd(&gsum[kp * DIM + lane], (unsigned long long)acc);
            acc = 0; kp = kc;
        }
        acc += (long long)rintf(v * FIXS);
        kc = k1; v = v1;
    }
    if (kc != kp) {
        atomicAdd(&gsum[kp * DIM + lane], (unsigned long long)acc);
        acc = 0; kp = kc;
    }
    acc += (long long)rintf(v * FIXS);
    atomicAdd(&gsum[kp * DIM + lane], (unsigned long long)acc);
}

// ---------------------------------------------------------------------------
// Finalize: EMA + division for centroid_sum and vq outputs.
// ---------------------------------------------------------------------------
__global__ __launch_bounds__(512) void finalize_kernel(
    const unsigned long long* __restrict__ gsum,
    const float* __restrict__ cs_old, const float* __restrict__ out_cn,
    float* __restrict__ out_vq, float* __restrict__ out_cs)
{
    int gid = blockIdx.x * 512 + threadIdx.x;
    if (gid >= KCB * DIM) return;
    int k = gid >> 6;
    long long g = (long long)gsum[gid];
    float scs = (float)((double)g * (1.0 / 262144.0));
    float ncs = cs_old[gid] * 0.99f + scs * 0.01f;
    out_cs[gid] = ncs;
    out_vq[gid] = ncs / out_cn[k];
}

// ---------------------------------------------------------------------------
extern "C" void kernel_launch(void* const* d_in, const int* in_sizes, int n_in,
                              void* d_out, int out_size, void* d_ws, size_t ws_size,
                              hipStream_t stream)
{
    const float* x      = (const float*)d_in[0];
    const float* vq     = (const float*)d_in[1];
    const float* cs_old = (const float*)d_in[2];
    const float* cn_old = (const float*)d_in[3];

    float* out_q  = (float*)d_out;
    float* out_vq = out_q + (size_t)N_TOK * DIM;
    float* out_cs = out_vq + (size_t)KCB * DIM;
    float* out_cn = out_cs + (size_t)KCB * DIM;

    char* ws = (char*)d_ws;
    int*    idx       = (int*)(ws);                              // 1 MB
    int*    flag_list = (int*)(ws + (1 << 20));                  // 1 MB (reused as sorted)
    int*    sorted    = flag_list;                               // refine consumes flags first
    int*    flag_cnt  = (int*)(ws + (2 << 20));                  // 4 B
    float*  qneg      = (float*)(ws + (2 << 20) + 1024);         // 2 KB
    double* qd        = (double*)(ws + (2 << 20) + 4096);        // 4 KB
    int*    counts    = (int*)(ws + (2 << 20) + 8192);           // 2 KB
    int*    cursor    = (int*)(ws + (2 << 20) + 10240);          // 2 KB
    unsigned long long* gsum =
        (unsigned long long*)(ws + (2 << 20) + 12288);           // 256 KB
    char*   vqh_img   = ws + (2 << 20) + 12288 + 262144;         // 64 KB
    char*   vql_img   = vqh_img + 65536;                         // 64 KB

    prep_kernel<<<16, 512, 0, stream>>>(vq, qneg, qd, vqh_img, vql_img,
                                        counts, flag_cnt, gsum);
    argmin_mfma_kernel<<<N_TOK / 256, 512, 0, stream>>>(x, vq, qneg, idx,
                                                        flag_cnt, flag_list,
                                                        out_q, counts,
                                                        vqh_img, vql_img);
    refine_kernel<<<256, 256, 0, stream>>>(x, vq, qd, flag_cnt, flag_list,
                                           idx, out_q, counts);
    scan_ema_kernel<<<1, 512, 0, stream>>>(counts, cursor, cn_old, out_cn);
    scatter_kernel<<<N_TOK / 1024, 512, 0, stream>>>(idx, cursor, sorted);
    gather_kernel<<<N_TOK / 256, 256, 0, stream>>>(x, sorted, gsum);
    finalize_kernel<<<KCB * DIM / 512, 512, 0, stream>>>(gsum, cs_old, out_cn,
                                                         out_vq, out_cs);
}